// Round 6
// baseline (330.388 us; speedup 1.0000x reference)
//
#include <hip/hip_runtime.h>

// Problem constants (fixed by setup_inputs): B=8, C=6, H=W=1024, k=5.
#define IMG_H 1024
#define IMG_W 1024
#define HW    (IMG_H * IMG_W)
#define HW4   (HW / 4)    // float4 units per channel
#define NCLS  6
#define NBATCH 8
// Full-width strip tile: 1024 wide x TH tall, HR = TH+4 halo rows.
#define TH 8
#define HR 12
#define CSW 1032          // colsum row: 4 zero-pad + 1024 + 4 zero-pad (u32/px)

// ---------------------------------------------------------------------------
// R6: full-width strips so every wave-level load is contiguous (64 lanes x
// 16 B = 1 KB per instruction, 4 KB per row per stream) instead of 256 B
// fragments. Halo packed 1 B/px (p | t<<3, both <= 5); vertical 5-tap sums
// packed (s1p|s2p<<8|s1t<<16|s2t<<24) -- fields bounded by 25/125 so 8 bits
// suffice; horizontal pass unpacks and uses exact integer variance
// var = (25*s2 - s1^2)/600. colsum done in two 4-row batches to keep LDS at
// 28.8 KB -> 5 blocks/CU.
// ---------------------------------------------------------------------------
__global__ __launch_bounds__(256, 4) void fused_loss_kernel(
    const float* __restrict__ pred, const int* __restrict__ tgt,
    float* __restrict__ out) {
  __shared__ unsigned int halo32[HR * 256];   // 12 rows x 256 words (4 px/word) = 12 KB
  __shared__ unsigned int colsum[4 * CSW];    // 4 rows x 1032 = 16.5 KB
  __shared__ float wsum[4];

  const int tid = threadIdx.x;
  // Swizzle so each XCD gets contiguous strips (halo overlap stays in-L2).
  const int job = (blockIdx.x & 7) * 128 + (blockIdx.x >> 3);  // bijective on [0,1024)
  const int img = job >> 7;          // 8 images
  const int y0  = (job & 127) * TH;  // 128 strips of 8 rows
  const float* pimg = pred + (size_t)img * NCLS * HW;
  const int*   timg = tgt  + (size_t)img * HW;

  // Zero the horizontal pad columns of colsum once (stage 2 never writes them).
  if (tid < 32) {
    const int r = tid >> 3, j = tid & 7;
    colsum[r * CSW + ((j < 4) ? j : 1024 + j)] = 0u;
  }

  // Stage 1: argmax + pack for 12 halo rows. Wave reads are fully contiguous:
  // lanes cover 64*16 B = 1 KB per channel per instruction.
  for (int k = 0; k < HR * 256; k += 256) {
    const int id  = k + tid;
    const int row = id >> 8;          // halo row 0..11
    const int g   = id & 255;         // 4-px group
    const int gy  = y0 + row - 2;
    unsigned int w = 0u;              // zero padding identity (p=t=0)
    if ((unsigned)gy < IMG_H) {
      const float4* p = (const float4*)(pimg + (size_t)gy * IMG_W) + g;
      float4 best = p[0];
      int cx = 0, cy = 0, cz = 0, cw = 0;
#pragma unroll
      for (int c = 1; c < NCLS; ++c) {   // jnp.argmax: first max (strict >)
        const float4 v = p[(size_t)c * HW4];
        if (v.x > best.x) { best.x = v.x; cx = c; }
        if (v.y > best.y) { best.y = v.y; cy = c; }
        if (v.z > best.z) { best.z = v.z; cz = c; }
        if (v.w > best.w) { best.w = v.w; cw = c; }
      }
      const int4 t4 = *((const int4*)(timg + (size_t)gy * IMG_W) + g);
      w = (unsigned)(cx | (t4.x << 3))
        | ((unsigned)(cy | (t4.y << 3)) << 8)
        | ((unsigned)(cz | (t4.z << 3)) << 16)
        | ((unsigned)(cw | (t4.w << 3)) << 24);
    }
    halo32[row * 256 + g] = w;
  }
  __syncthreads();

  float acc = 0.f;
#pragma unroll
  for (int bb = 0; bb < 2; ++bb) {
    // Stage 2: vertical 5-tap sums for output rows bb*4 .. bb*4+3.
    for (int k = 0; k < 4 * 256; k += 256) {
      const int id = k + tid;
      const int r  = id >> 8;         // colsum row 0..3 (output row bb*4+r)
      const int g  = id & 255;
      const unsigned int* h = &halo32[(bb * 4 + r) * 256 + g];
      unsigned s1p[4] = {0,0,0,0}, s2p[4] = {0,0,0,0};
      unsigned s1t[4] = {0,0,0,0}, s2t[4] = {0,0,0,0};
#pragma unroll
      for (int d = 0; d < 5; ++d) {
        const unsigned wv = h[d * 256];
#pragma unroll
        for (int j = 0; j < 4; ++j) {
          const unsigned pv = (wv >> (8 * j)) & 7u;
          const unsigned tv = (wv >> (8 * j + 3)) & 7u;
          s1p[j] += pv; s2p[j] += pv * pv;
          s1t[j] += tv; s2t[j] += tv * tv;
        }
      }
      uint4 o;
      o.x = s1p[0] | (s2p[0] << 8) | (s1t[0] << 16) | (s2t[0] << 24);
      o.y = s1p[1] | (s2p[1] << 8) | (s1t[1] << 16) | (s2t[1] << 24);
      o.z = s1p[2] | (s2p[2] << 8) | (s1t[2] << 16) | (s2t[2] << 24);
      o.w = s1p[3] | (s2p[3] << 8) | (s1t[3] << 16) | (s2t[3] << 24);
      *(uint4*)&colsum[r * CSW + 4 + 4 * g] = o;   // cc = col+4, 16B-aligned
    }
    __syncthreads();

    // Stage 3: horizontal 5-tap, exact-int variance, squared std diff.
    for (int k = 0; k < 4 * 256; k += 256) {
      const int id = k + tid;
      const int r  = id >> 8;
      const int g  = id & 255;        // output cols 4g..4g+3
      const unsigned int* cs = &colsum[r * CSW + 4 * g];  // w[i] = cc 4g+i
      const uint4 wa = *(const uint4*)(cs);
      const uint4 wb = *(const uint4*)(cs + 4);
      const uint4 wc = *(const uint4*)(cs + 8);
      const unsigned w[12] = {wa.x, wa.y, wa.z, wa.w,
                              wb.x, wb.y, wb.z, wb.w,
                              wc.x, wc.y, wc.z, wc.w};
#pragma unroll
      for (int j = 0; j < 4; ++j) {   // col 4g+j needs cc 4g+j+2 .. 4g+j+6
        int s1p = 0, s2p = 0, s1t = 0, s2t = 0;
#pragma unroll
        for (int d = 0; d < 5; ++d) {
          const unsigned v = w[j + 2 + d];
          s1p += (int)(v & 0xFFu);
          s2p += (int)((v >> 8) & 0xFFu);
          s1t += (int)((v >> 16) & 0xFFu);
          s2t += (int)(v >> 24);
        }
        const float varp = (float)(25 * s2p - s1p * s1p) * (1.0f / 600.0f);
        const float vart = (float)(25 * s2t - s1t * s1t) * (1.0f / 600.0f);
        const float dd = sqrtf(varp) - sqrtf(vart);
        acc += dd * dd;
      }
    }
    __syncthreads();   // protects colsum reuse (bb=0) and wsum (after bb=1)
  }

  // Wave (64-lane) shuffle reduce, cross-wave via LDS, one atomic per block.
#pragma unroll
  for (int off = 32; off > 0; off >>= 1) acc += __shfl_down(acc, off, 64);
  const int lane = tid & 63;
  const int wid  = tid >> 6;
  if (lane == 0) wsum[wid] = acc;
  __syncthreads();
  if (tid == 0) {
    const float t = wsum[0] + wsum[1] + wsum[2] + wsum[3];
    atomicAdd(out, t * (1.0f / 8388608.0f));  // exact: B*H*W = 2^23
  }
}

extern "C" void kernel_launch(void* const* d_in, const int* in_sizes, int n_in,
                              void* d_out, int out_size, void* d_ws, size_t ws_size,
                              hipStream_t stream) {
  const float* pred = (const float*)d_in[0];
  const int* tgt    = (const int*)d_in[1];
  // d_in[2] = kernel_size (always 5 here; kernel is specialized).
  float* out = (float*)d_out;
  (void)d_ws; (void)ws_size;

  hipMemsetAsync(d_out, 0, sizeof(float), stream);

  // 8 images x 128 strips = 1024 blocks of 256.
  fused_loss_kernel<<<dim3(1024), dim3(256), 0, stream>>>(pred, tgt, out);
}

// Round 7
// 319.958 us; speedup vs baseline: 1.0326x; 1.0326x over previous
//
#include <hip/hip_runtime.h>

// Problem constants (fixed by setup_inputs): B=8, C=6, H=W=1024, k=5.
#define IMG_H 1024
#define IMG_W 1024
#define HW    (IMG_H * IMG_W)
#define HW4   (HW / 4)    // float4 / 4-px groups per channel (2^18)
#define NCLS  6
#define NBATCH 8
// Stencil strip: full width x TH rows, HR = TH+4 halo rows.
#define TH 8
#define HR 12
#define CSW 1032          // colsum row: 4 zero-pad + 1024 + 4 zero-pad (u32/px)

// ---------------------------------------------------------------------------
// Kernel A: pure streaming argmax + pack. One thread = 4 pixels. No LDS, no
// barriers, no divergence. Reads 6 float4 streams + 1 int4, writes uchar4
// (p | t<<3 per byte, both values <= 5). This isolates the streaming read
// path from the stencil: it should run at HBM-class BW (~6 TB/s).
// ---------------------------------------------------------------------------
__global__ __launch_bounds__(256) void argmax_pack_kernel(
    const float* __restrict__ pred, const int* __restrict__ tgt,
    unsigned char* __restrict__ packed) {
  const int idx = blockIdx.x * 256 + threadIdx.x;   // [0, NBATCH*HW4)
  const int b   = idx >> 18;                        // HW4 = 2^18
  const int g   = idx & (HW4 - 1);
  const float4* p = (const float4*)(pred + (size_t)b * NCLS * HW) + g;
  float4 best = p[0];
  int cx = 0, cy = 0, cz = 0, cw = 0;
#pragma unroll
  for (int c = 1; c < NCLS; ++c) {    // jnp.argmax: first max (strict >)
    const float4 v = p[(size_t)c * HW4];
    if (v.x > best.x) { best.x = v.x; cx = c; }
    if (v.y > best.y) { best.y = v.y; cy = c; }
    if (v.z > best.z) { best.z = v.z; cz = c; }
    if (v.w > best.w) { best.w = v.w; cw = c; }
  }
  const int4 t4 = ((const int4*)(tgt + (size_t)b * HW))[g];
  uchar4 o;
  o.x = (unsigned char)(cx | (t4.x << 3));
  o.y = (unsigned char)(cy | (t4.y << 3));
  o.z = (unsigned char)(cz | (t4.z << 3));
  o.w = (unsigned char)(cw | (t4.w << 3));
  ((uchar4*)packed)[idx] = o;
}

// ---------------------------------------------------------------------------
// Kernel B: 5x5 separable box-sum stencil on the packed byte map (R6 stages
// 2-3 verbatim, verified absmax 0.0). Vertical 5-tap sums packed
// (s1p|s2p<<8|s1t<<16|s2t<<24), fields bounded by 25/125; exact integer
// variance var = (25*s2 - s1^2)/600; squared std-diff; block reduce; one
// atomicAdd scaled by exactly 1/2^23.
// ---------------------------------------------------------------------------
__global__ __launch_bounds__(256, 4) void stencil_loss_kernel(
    const unsigned int* __restrict__ packed32, float* __restrict__ out) {
  __shared__ unsigned int halo32[HR * 256];   // 12 rows x 256 words = 12 KB
  __shared__ unsigned int colsum[4 * CSW];    // 16.5 KB
  __shared__ float wsum[4];

  const int tid = threadIdx.x;
  const int job = blockIdx.x;        // [0, 1024)
  const int img = job >> 7;          // 8 images
  const int y0  = (job & 127) * TH;  // 128 strips of 8 rows
  const unsigned int* pw = packed32 + (size_t)img * (HW / 4);

  // Zero the horizontal pad columns of colsum (stage 2 never writes them).
  if (tid < 32) {
    const int r = tid >> 3, j = tid & 7;
    colsum[r * CSW + ((j < 4) ? j : 1024 + j)] = 0u;
  }

  // Stage 1: load 12 halo rows of packed words (4 px/word), contiguous.
  for (int k = 0; k < HR * 256; k += 256) {
    const int id  = k + tid;
    const int row = id >> 8;
    const int g   = id & 255;
    const int gy  = y0 + row - 2;
    unsigned int w = 0u;             // zero-padding identity (p=t=0)
    if ((unsigned)gy < IMG_H) w = pw[gy * 256 + g];
    halo32[row * 256 + g] = w;
  }
  __syncthreads();

  float acc = 0.f;
#pragma unroll
  for (int bb = 0; bb < 2; ++bb) {
    // Stage 2: vertical 5-tap sums for output rows bb*4 .. bb*4+3.
    for (int k = 0; k < 4 * 256; k += 256) {
      const int id = k + tid;
      const int r  = id >> 8;
      const int g  = id & 255;
      const unsigned int* h = &halo32[(bb * 4 + r) * 256 + g];
      unsigned s1p[4] = {0,0,0,0}, s2p[4] = {0,0,0,0};
      unsigned s1t[4] = {0,0,0,0}, s2t[4] = {0,0,0,0};
#pragma unroll
      for (int d = 0; d < 5; ++d) {
        const unsigned wv = h[d * 256];
#pragma unroll
        for (int j = 0; j < 4; ++j) {
          const unsigned pv = (wv >> (8 * j)) & 7u;
          const unsigned tv = (wv >> (8 * j + 3)) & 7u;
          s1p[j] += pv; s2p[j] += pv * pv;
          s1t[j] += tv; s2t[j] += tv * tv;
        }
      }
      uint4 o;
      o.x = s1p[0] | (s2p[0] << 8) | (s1t[0] << 16) | (s2t[0] << 24);
      o.y = s1p[1] | (s2p[1] << 8) | (s1t[1] << 16) | (s2t[1] << 24);
      o.z = s1p[2] | (s2p[2] << 8) | (s1t[2] << 16) | (s2t[2] << 24);
      o.w = s1p[3] | (s2p[3] << 8) | (s1t[3] << 16) | (s2t[3] << 24);
      *(uint4*)&colsum[r * CSW + 4 + 4 * g] = o;
    }
    __syncthreads();

    // Stage 3: horizontal 5-tap, exact-int variance, squared std diff.
    for (int k = 0; k < 4 * 256; k += 256) {
      const int id = k + tid;
      const int r  = id >> 8;
      const int g  = id & 255;        // output cols 4g..4g+3
      const unsigned int* cs = &colsum[r * CSW + 4 * g];
      const uint4 wa = *(const uint4*)(cs);
      const uint4 wb = *(const uint4*)(cs + 4);
      const uint4 wc = *(const uint4*)(cs + 8);
      const unsigned w[12] = {wa.x, wa.y, wa.z, wa.w,
                              wb.x, wb.y, wb.z, wb.w,
                              wc.x, wc.y, wc.z, wc.w};
#pragma unroll
      for (int j = 0; j < 4; ++j) {
        int s1p = 0, s2p = 0, s1t = 0, s2t = 0;
#pragma unroll
        for (int d = 0; d < 5; ++d) {
          const unsigned v = w[j + 2 + d];
          s1p += (int)(v & 0xFFu);
          s2p += (int)((v >> 8) & 0xFFu);
          s1t += (int)((v >> 16) & 0xFFu);
          s2t += (int)(v >> 24);
        }
        const float varp = (float)(25 * s2p - s1p * s1p) * (1.0f / 600.0f);
        const float vart = (float)(25 * s2t - s1t * s1t) * (1.0f / 600.0f);
        const float dd = sqrtf(varp) - sqrtf(vart);
        acc += dd * dd;
      }
    }
    __syncthreads();
  }

  // Wave (64-lane) shuffle reduce, cross-wave via LDS, one atomic per block.
#pragma unroll
  for (int off = 32; off > 0; off >>= 1) acc += __shfl_down(acc, off, 64);
  const int lane = tid & 63;
  const int wid  = tid >> 6;
  if (lane == 0) wsum[wid] = acc;
  __syncthreads();
  if (tid == 0) {
    const float t = wsum[0] + wsum[1] + wsum[2] + wsum[3];
    atomicAdd(out, t * (1.0f / 8388608.0f));  // exact: B*H*W = 2^23
  }
}

extern "C" void kernel_launch(void* const* d_in, const int* in_sizes, int n_in,
                              void* d_out, int out_size, void* d_ws, size_t ws_size,
                              hipStream_t stream) {
  const float* pred = (const float*)d_in[0];
  const int* tgt    = (const int*)d_in[1];
  // d_in[2] = kernel_size (always 5 here; kernel is specialized).
  float* out = (float*)d_out;
  unsigned char* packed = (unsigned char*)d_ws;   // needs 8 MiB of ws

  hipMemsetAsync(d_out, 0, sizeof(float), stream);

  // A: 2^21 4-px groups -> 8192 blocks of 256.
  argmax_pack_kernel<<<dim3(NBATCH * HW4 / 256), dim3(256), 0, stream>>>(
      pred, tgt, packed);

  // B: 8 images x 128 strips = 1024 blocks of 256.
  stencil_loss_kernel<<<dim3(1024), dim3(256), 0, stream>>>(
      (const unsigned int*)packed, out);
}

// Round 9
// 302.598 us; speedup vs baseline: 1.0918x; 1.0574x over previous
//
#include <hip/hip_runtime.h>

// Problem constants (fixed by setup_inputs): B=8, C=6, H=W=1024, k=5.
#define IMG_H 1024
#define IMG_W 1024
#define HW    (IMG_H * IMG_W)
#define HW4   (HW / 4)    // 4-px groups per channel (2^18)
#define NCLS  6
#define NBATCH 8
// Stencil strip: full width x TH rows, HR = TH+4 halo rows.
#define TH 8
#define HR 12
#define CSW 1032          // colsum row: 4 zero-pad + 1024 + 4 zero-pad (u32/px)

// Native clang vector types — __builtin_nontemporal_load requires true
// vectors, not HIP's HIP_vector_type wrapper classes.
typedef float fv4 __attribute__((ext_vector_type(4)));
typedef int   iv4 __attribute__((ext_vector_type(4)));

__device__ __forceinline__ fv4 ntload_f4(const float* p) {
  return __builtin_nontemporal_load((const fv4*)p);
}
__device__ __forceinline__ iv4 ntload_i4(const int* p) {
  return __builtin_nontemporal_load((const iv4*)p);
}

// ---------------------------------------------------------------------------
// Kernel A (R8 fixed): streaming argmax+pack restructured for DRAM row
// locality. Each wave owns 256 consecutive 4-px groups (1024 px = 4 KB per
// channel); loads are issued channel-major, 4 x 1 KB back-to-back, so each
// stream delivers a full 4-KB page burst per clause instead of one 1-KB
// touch. Nontemporal: inputs have zero reuse (restored every iteration).
// jnp.argmax = first max -> ascending c, strict '>'.
// ---------------------------------------------------------------------------
__global__ __launch_bounds__(256) void argmax_pack_kernel(
    const float* __restrict__ pred, const int* __restrict__ tgt,
    unsigned char* __restrict__ packed) {
  const int gtid = blockIdx.x * 256 + threadIdx.x;   // [0, 2^19)
  const int wave = gtid >> 6;                        // [0, 8192)
  const int lane = gtid & 63;
  const int img  = wave >> 10;                       // 1024 waves per image
  const int G0   = (wave & 1023) * 256;              // group base within image
  const float* pb = pred + (size_t)img * NCLS * HW;
  const int*   tb = tgt  + (size_t)img * HW;

  int g[4];
#pragma unroll
  for (int j = 0; j < 4; ++j) g[j] = G0 + j * 64 + lane;

  fv4 best[4];
  iv4 idx[4];
#pragma unroll
  for (int j = 0; j < 4; ++j) {
    best[j] = ntload_f4(pb + (size_t)g[j] * 4);
    idx[j] = (iv4)0;
  }
#pragma unroll
  for (int c = 1; c < NCLS; ++c) {
    fv4 v[4];
#pragma unroll
    for (int j = 0; j < 4; ++j)
      v[j] = ntload_f4(pb + ((size_t)c * HW4 + g[j]) * 4);
#pragma unroll
    for (int j = 0; j < 4; ++j) {
#pragma unroll
      for (int e = 0; e < 4; ++e) {
        if (v[j][e] > best[j][e]) { best[j][e] = v[j][e]; idx[j][e] = c; }
      }
    }
  }
  iv4 t[4];
#pragma unroll
  for (int j = 0; j < 4; ++j) t[j] = ntload_i4(tb + (size_t)g[j] * 4);
#pragma unroll
  for (int j = 0; j < 4; ++j) {
    uchar4 o;
    o.x = (unsigned char)(idx[j][0] | (t[j][0] << 3));
    o.y = (unsigned char)(idx[j][1] | (t[j][1] << 3));
    o.z = (unsigned char)(idx[j][2] | (t[j][2] << 3));
    o.w = (unsigned char)(idx[j][3] | (t[j][3] << 3));
    ((uchar4*)packed)[(size_t)img * HW4 + g[j]] = o;
  }
}

// ---------------------------------------------------------------------------
// Kernel B: 5x5 separable box-sum stencil on the packed byte map (verified
// absmax 0.0 in R7). Vertical 5-tap sums packed (s1p|s2p<<8|s1t<<16|s2t<<24),
// fields bounded by 25/125; exact integer variance var = (25*s2 - s1^2)/600;
// squared std-diff; block reduce; one atomicAdd scaled by exactly 1/2^23.
// ---------------------------------------------------------------------------
__global__ __launch_bounds__(256, 4) void stencil_loss_kernel(
    const unsigned int* __restrict__ packed32, float* __restrict__ out) {
  __shared__ unsigned int halo32[HR * 256];   // 12 rows x 256 words = 12 KB
  __shared__ unsigned int colsum[4 * CSW];    // 16.5 KB
  __shared__ float wsum[4];

  const int tid = threadIdx.x;
  const int job = blockIdx.x;        // [0, 1024)
  const int img = job >> 7;          // 8 images
  const int y0  = (job & 127) * TH;  // 128 strips of 8 rows
  const unsigned int* pw = packed32 + (size_t)img * (HW / 4);

  // Zero the horizontal pad columns of colsum (stage 2 never writes them).
  if (tid < 32) {
    const int r = tid >> 3, j = tid & 7;
    colsum[r * CSW + ((j < 4) ? j : 1024 + j)] = 0u;
  }

  // Stage 1: load 12 halo rows of packed words (4 px/word), contiguous.
  for (int k = 0; k < HR * 256; k += 256) {
    const int id  = k + tid;
    const int row = id >> 8;
    const int g   = id & 255;
    const int gy  = y0 + row - 2;
    unsigned int w = 0u;             // zero-padding identity (p=t=0)
    if ((unsigned)gy < IMG_H) w = pw[gy * 256 + g];
    halo32[row * 256 + g] = w;
  }
  __syncthreads();

  float acc = 0.f;
#pragma unroll
  for (int bb = 0; bb < 2; ++bb) {
    // Stage 2: vertical 5-tap sums for output rows bb*4 .. bb*4+3.
    for (int k = 0; k < 4 * 256; k += 256) {
      const int id = k + tid;
      const int r  = id >> 8;
      const int g  = id & 255;
      const unsigned int* h = &halo32[(bb * 4 + r) * 256 + g];
      unsigned s1p[4] = {0,0,0,0}, s2p[4] = {0,0,0,0};
      unsigned s1t[4] = {0,0,0,0}, s2t[4] = {0,0,0,0};
#pragma unroll
      for (int d = 0; d < 5; ++d) {
        const unsigned wv = h[d * 256];
#pragma unroll
        for (int j = 0; j < 4; ++j) {
          const unsigned pv = (wv >> (8 * j)) & 7u;
          const unsigned tv = (wv >> (8 * j + 3)) & 7u;
          s1p[j] += pv; s2p[j] += pv * pv;
          s1t[j] += tv; s2t[j] += tv * tv;
        }
      }
      uint4 o;
      o.x = s1p[0] | (s2p[0] << 8) | (s1t[0] << 16) | (s2t[0] << 24);
      o.y = s1p[1] | (s2p[1] << 8) | (s1t[1] << 16) | (s2t[1] << 24);
      o.z = s1p[2] | (s2p[2] << 8) | (s1t[2] << 16) | (s2t[2] << 24);
      o.w = s1p[3] | (s2p[3] << 8) | (s1t[3] << 16) | (s2t[3] << 24);
      *(uint4*)&colsum[r * CSW + 4 + 4 * g] = o;
    }
    __syncthreads();

    // Stage 3: horizontal 5-tap, exact-int variance, squared std diff.
    for (int k = 0; k < 4 * 256; k += 256) {
      const int id = k + tid;
      const int r  = id >> 8;
      const int g  = id & 255;        // output cols 4g..4g+3
      const unsigned int* cs = &colsum[r * CSW + 4 * g];
      const uint4 wa = *(const uint4*)(cs);
      const uint4 wb = *(const uint4*)(cs + 4);
      const uint4 wc = *(const uint4*)(cs + 8);
      const unsigned w[12] = {wa.x, wa.y, wa.z, wa.w,
                              wb.x, wb.y, wb.z, wb.w,
                              wc.x, wc.y, wc.z, wc.w};
#pragma unroll
      for (int j = 0; j < 4; ++j) {
        int s1p = 0, s2p = 0, s1t = 0, s2t = 0;
#pragma unroll
        for (int d = 0; d < 5; ++d) {
          const unsigned v = w[j + 2 + d];
          s1p += (int)(v & 0xFFu);
          s2p += (int)((v >> 8) & 0xFFu);
          s1t += (int)((v >> 16) & 0xFFu);
          s2t += (int)(v >> 24);
        }
        const float varp = (float)(25 * s2p - s1p * s1p) * (1.0f / 600.0f);
        const float vart = (float)(25 * s2t - s1t * s1t) * (1.0f / 600.0f);
        const float dd = sqrtf(varp) - sqrtf(vart);
        acc += dd * dd;
      }
    }
    __syncthreads();
  }

  // Wave (64-lane) shuffle reduce, cross-wave via LDS, one atomic per block.
#pragma unroll
  for (int off = 32; off > 0; off >>= 1) acc += __shfl_down(acc, off, 64);
  const int lane = tid & 63;
  const int wid  = tid >> 6;
  if (lane == 0) wsum[wid] = acc;
  __syncthreads();
  if (tid == 0) {
    const float t = wsum[0] + wsum[1] + wsum[2] + wsum[3];
    atomicAdd(out, t * (1.0f / 8388608.0f));  // exact: B*H*W = 2^23
  }
}

extern "C" void kernel_launch(void* const* d_in, const int* in_sizes, int n_in,
                              void* d_out, int out_size, void* d_ws, size_t ws_size,
                              hipStream_t stream) {
  const float* pred = (const float*)d_in[0];
  const int* tgt    = (const int*)d_in[1];
  // d_in[2] = kernel_size (always 5 here; kernel is specialized).
  float* out = (float*)d_out;
  unsigned char* packed = (unsigned char*)d_ws;   // needs 8 MiB of ws

  (void)hipMemsetAsync(d_out, 0, sizeof(float), stream);

  // A: 2^19 threads (4 groups each) -> 2048 blocks of 256.
  argmax_pack_kernel<<<dim3(2048), dim3(256), 0, stream>>>(pred, tgt, packed);

  // B: 8 images x 128 strips = 1024 blocks of 256.
  stencil_loss_kernel<<<dim3(1024), dim3(256), 0, stream>>>(
      (const unsigned int*)packed, out);
}